// Round 3
// baseline (733.031 us; speedup 1.0000x reference)
//
#include <hip/hip_runtime.h>
#include <hip/hip_bf16.h>

#define NN 100000
#define DD 128
#define MM 3
#define EE 1600000
#define NBUK ((NN + 127) / 128)   // 782 dst-buckets per meta-path
#define CAP 2336                  // per-bucket edge capacity (mean 2046.5, +6.4 sigma)
#define CSRTOT ((size_t)NBUK * CAP)
#define TILE_E 2048
#define NTILES ((EE + TILE_E - 1) / TILE_E)  // 782
#define TH_PITCH 784              // thist inner pitch (tiles), 16B-aligned
#define HSCALE 64.0f
#define HINV (1.0f / 64.0f)

typedef unsigned int uint32_hip;
typedef short short8 __attribute__((ext_vector_type(8)));
typedef float floatx4 __attribute__((ext_vector_type(4)));
typedef float floatx2 __attribute__((ext_vector_type(2)));

// ---- bf16 helpers ----
__device__ __forceinline__ float bf2f(short s) {
  return __uint_as_float(((uint32_hip)(unsigned short)s) << 16);
}
__device__ __forceinline__ unsigned short f2bf(float f) {
  union { __hip_bfloat16 b; unsigned short u; } cv;
  cv.b = __float2bfloat16(f);
  return cv.u;
}
__device__ __forceinline__ uint32_hip packbf2(float x, float y) {
  return (uint32_hip)f2bf(x) | ((uint32_hip)f2bf(y) << 16);
}
__device__ __forceinline__ float tanh_apx(float x) {
  float e = __expf(2.0f * x);
  return 1.0f - 2.0f / (e + 1.0f);
}
// pack 4 floats -> 4 fp8 e4m3 (OCP on gfx950) in one uint
__device__ __forceinline__ uint32_hip pack_fp8x4(float a, float b, float c, float d) {
  uint32_hip w = 0;
  w = __builtin_amdgcn_cvt_pk_fp8_f32(a, b, w, false);  // bytes 0,1
  w = __builtin_amdgcn_cvt_pk_fp8_f32(c, d, w, true);   // bytes 2,3
  return w;
}
// fp16 (in low 16 bits) -> f32
__device__ __forceinline__ float h2f(uint32_hip u) {
  union { unsigned short us; _Float16 h; } cv;
  cv.us = (unsigned short)u;
  return (float)cv.h;
}
__device__ __forceinline__ unsigned short f2h(float f) {
  union { unsigned short us; _Float16 h; } cv;
  cv.h = (_Float16)f;
  return cv.us;
}
// decode 8 fp8 (uint2) -> 8 floats
__device__ __forceinline__ void dec8(uint2 hv, float* f) {
  floatx2 p0 = __builtin_amdgcn_cvt_pk_f32_fp8((int)hv.x, false);
  floatx2 p1 = __builtin_amdgcn_cvt_pk_f32_fp8((int)hv.x, true);
  floatx2 p2 = __builtin_amdgcn_cvt_pk_f32_fp8((int)hv.y, false);
  floatx2 p3 = __builtin_amdgcn_cvt_pk_f32_fp8((int)hv.y, true);
  f[0] = p0.x; f[1] = p0.y; f[2] = p1.x; f[3] = p1.y;
  f[4] = p2.x; f[5] = p2.y; f[6] = p3.x; f[7] = p3.y;
}

// ---------- per-tile bucket histogram -> thist[m][bucket][tile] ----------
__global__ __launch_bounds__(256) void hist_kernel(const int* __restrict__ e0,
                                                   const int* __restrict__ e1,
                                                   const int* __restrict__ e2,
                                                   int* __restrict__ thist) {
  __shared__ int hist[NBUK];
  int m = blockIdx.y, tile = blockIdx.x, t = threadIdx.x;
  const int* ei = (m == 0) ? e0 : (m == 1) ? e1 : e2;
  const int* dst = ei + EE;
  int beg = tile * TILE_E, end = min(beg + TILE_E, EE);
  for (int b = t; b < NBUK; b += 256) hist[b] = 0;
  __syncthreads();
  for (int e = beg + t; e < end; e += 256) atomicAdd(&hist[dst[e] >> 7], 1);
  __syncthreads();
  int* th = thist + (size_t)m * NBUK * TH_PITCH + tile;
  for (int b = t; b < NBUK; b += 256) th[(size_t)b * TH_PITCH] = hist[b];
}

// ---------- exclusive scan across tiles per (bucket, m); deterministic bases ----------
// thist[m][b][t] <- b*CAP + (sum of counts of tiles < t); bcur[m][b] = b*CAP + total
__global__ __launch_bounds__(256) void scan_kernel(int* __restrict__ thist,
                                                   int* __restrict__ bcur) {
  __shared__ int sw[256];
  int b = blockIdx.x, m = blockIdx.y, t = threadIdx.x;
  int* th = thist + ((size_t)m * NBUK + b) * TH_PITCH;
  int v[4];
  int s = 0;
#pragma unroll
  for (int j = 0; j < 4; ++j) {
    int tt = t * 4 + j;
    v[j] = (tt < NTILES) ? th[tt] : 0;
    s += v[j];
  }
  sw[t] = s;
  __syncthreads();
  for (int off = 1; off < 256; off <<= 1) {
    int u = (t >= off) ? sw[t - off] : 0;
    __syncthreads();
    sw[t] += u;
    __syncthreads();
  }
  int base = b * CAP + sw[t] - s;  // exclusive prefix for this thread's chunk
#pragma unroll
  for (int j = 0; j < 4; ++j) {
    int tt = t * 4 + j;
    if (tt < NTILES) th[tt] = base;
    base += v[j];
  }
  if (t == 255) bcur[m * NBUK + b] = b * CAP + sw[255];
}

// ---------- scatter edges to deterministic positions; LDS cursors only ----------
__global__ __launch_bounds__(256) void scatter_kernel(const int* __restrict__ e0,
                                                      const int* __restrict__ e1,
                                                      const int* __restrict__ e2,
                                                      const int* __restrict__ thist,
                                                      uint32_hip* __restrict__ ebuf) {
  __shared__ int cur[NBUK];
  int m = blockIdx.y, tile = blockIdx.x, t = threadIdx.x;
  const int* ei = (m == 0) ? e0 : (m == 1) ? e1 : e2;
  const int* dst = ei + EE;
  int beg = tile * TILE_E, end = min(beg + TILE_E, EE);
  const int* th = thist + (size_t)m * NBUK * TH_PITCH + tile;
  for (int b = t; b < NBUK; b += 256) cur[b] = th[(size_t)b * TH_PITCH];
  __syncthreads();
  uint32_hip* eb = ebuf + (size_t)m * CSRTOT;
  for (int e = beg + t; e < end; e += 256) {
    int d = dst[e];
    int pos = atomicAdd(&cur[d >> 7], 1);
    eb[pos] = (uint32_hip)ei[e] | ((uint32_hip)(d & 127) << 17);
  }
}

// ---------- in-place per-bucket counting sort; emits astart + deg (ushort) ----------
__global__ void bucket_sort_kernel(uint32_hip* __restrict__ ebuf, const int* __restrict__ bcur,
                                   int* __restrict__ astart, unsigned short* __restrict__ sdeg) {
  __shared__ uint32_hip ebl[CAP];
  __shared__ int cnt[128];
  __shared__ int pos[128];
  int m = blockIdx.y, b = blockIdx.x, t = threadIdx.x;
  int base = b * CAP;
  int ct = bcur[m * NBUK + b] - base;  // edges in this bucket
  uint32_hip* eb = ebuf + (size_t)m * CSRTOT + base;
  for (int e = t; e < ct; e += 256) ebl[e] = eb[e];
  if (t < 128) cnt[t] = 0;
  __syncthreads();
  for (int e = t; e < ct; e += 256) atomicAdd(&cnt[ebl[e] >> 17], 1);
  __syncthreads();
  if (t < 128) pos[t] = cnt[t];
  __syncthreads();
  for (int off = 1; off < 128; off <<= 1) {
    int v = (t < 128 && t >= off) ? pos[t - off] : 0;
    __syncthreads();
    if (t < 128) pos[t] += v;
    __syncthreads();
  }
  int node0 = b * 128;
  if (t < 128) {
    int excl = pos[t] - cnt[t];
    pos[t] = excl;  // bucket-relative cursor
    int node = node0 + t;
    if (node < NN) {
      astart[(size_t)m * NN + node] = base + excl;
      sdeg[(size_t)m * NN + node] = (unsigned short)cnt[t];
    }
  }
  __syncthreads();
  for (int e = t; e < ct; e += 256) {
    uint32_hip p = ebl[e];
    int q = atomicAdd(&pos[p >> 17], 1);
    eb[q] = p & 0x1FFFFu;  // src only, node-sorted, in place
  }
}

// ---------- embed fp16 source-norm into upper 15 bits of each CSR entry ----------
// entry = src | (fp16(rsqrt(deg[src]+1)) << 17). fp16 of a positive value has
// bit15 == 0, so it fits the 15 free bits exactly. sdeg (200KB/m) is L2-resident.
__global__ void norm_embed_kernel(uint32_hip* __restrict__ ebuf, const int* __restrict__ bcur,
                                  const unsigned short* __restrict__ sdeg) {
  int m = blockIdx.y, b = blockIdx.x, t = threadIdx.x;
  int base = b * CAP;
  int ct = bcur[m * NBUK + b] - base;
  uint32_hip* eb = ebuf + (size_t)m * CSRTOT + base;
  const unsigned short* sd = sdeg + (size_t)m * NN;
  for (int e = t; e < ct; e += 256) {
    uint32_hip s = eb[e] & 0x1FFFFu;
    float dv = rsqrtf((float)(sd[s] + 1));
    eb[e] = s | ((uint32_hip)f2h(dv) << 17);
  }
}

// ---------- embedding gather -> fp8 h (x64 scale), lives in d_out ----------
__global__ void embed_kernel(const int* __restrict__ x, const float* __restrict__ tbl,
                             uint32_hip* __restrict__ hq) {
  int i = blockIdx.x * 256 + threadIdx.x;
  if (i < NN * 32) {
    int n = i >> 5;
    int c = i & 31;
    float4 v = ((const float4*)tbl)[(size_t)x[n] * 32 + c];
    hq[(size_t)n * 32 + c] =
        pack_fp8x4(v.x * HSCALE, v.y * HSCALE, v.z * HSCALE, v.w * HSCALE);
  }
}

// ---------- normalized aggregation (fp8 h -> bf16 z) ----------
// 4 nodes per wave, 16 lanes per node, dwordx2 (8 fp8) per lane per edge.
// Norm comes pre-quantized (fp16) from the CSR entry -> no sdeg gather, no rsqrt.
// CSR entries for iteration i+1 are prefetched during iteration i.
__global__ __launch_bounds__(256) void agg_kernel(const uint32_hip* __restrict__ hq,
                                                  const unsigned short* __restrict__ sdeg,
                                                  const int* __restrict__ astart,
                                                  const uint32_hip* __restrict__ csr,
                                                  uint32_hip* __restrict__ zall) {
  int m = blockIdx.y;
  const unsigned short* sd = sdeg + (size_t)m * NN;
  const int* as_ = astart + (size_t)m * NN;
  const uint32_hip* cs = csr + (size_t)m * CSRTOT;
  uint32_hip* zo = zall + (size_t)m * NN * 64;
  int t = threadIdx.x;
  int wave = t >> 6, lane = t & 63;
  int g = lane >> 4, l = lane & 15;  // group (node) within wave, lane within group
  int n = blockIdx.x * 16 + wave * 4 + g;  // NN = 100000 = 16 * 6250 -> exact grid
  int deg = sd[n];
  float di = rsqrtf((float)(deg + 1));

  float ac[8];
  {
    uint2 hv = *(const uint2*)(hq + (size_t)n * 32 + l * 2);
    float f[8];
    dec8(hv, f);
#pragma unroll
    for (int j = 0; j < 8; ++j) ac[j] = di * f[j];
  }

  int e = as_[n];
  int end = e + deg;
  bool v0 = e < end, v1 = (e + 1) < end;
  uint32_hip c0 = cs[v0 ? e : 0];
  uint32_hip c1 = cs[v1 ? e + 1 : 0];
  while (__any(v0)) {
    // prefetch next iteration's CSR entries (clamped; predicated out via norm=0)
    int en = e + 2;
    bool u0 = en < end, u1 = (en + 1) < end;
    uint32_hip d0 = cs[u0 ? en : 0];
    uint32_hip d1 = cs[u1 ? en + 1 : 0];
    // process current pair
    float n0 = v0 ? h2f(c0 >> 17) : 0.f;
    float n1 = v1 ? h2f(c1 >> 17) : 0.f;
    int s0 = c0 & 0x1FFFF, s1 = c1 & 0x1FFFF;
    uint2 h0 = *(const uint2*)(hq + (size_t)s0 * 32 + l * 2);
    uint2 h1 = *(const uint2*)(hq + (size_t)s1 * 32 + l * 2);
    float f0[8], f1[8];
    dec8(h0, f0);
    dec8(h1, f1);
#pragma unroll
    for (int j = 0; j < 8; ++j) ac[j] = fmaf(n0, f0[j], ac[j]);
#pragma unroll
    for (int j = 0; j < 8; ++j) ac[j] = fmaf(n1, f1[j], ac[j]);
    e = en;
    v0 = u0;
    v1 = u1;
    c0 = d0;
    c1 = d1;
  }

  float sc = di * HINV;
  uint4 w;
  w.x = packbf2(ac[0] * sc, ac[1] * sc);
  w.y = packbf2(ac[2] * sc, ac[3] * sc);
  w.z = packbf2(ac[4] * sc, ac[5] * sc);
  w.w = packbf2(ac[6] * sc, ac[7] * sc);
  *(uint4*)(zo + (size_t)n * 64 + l * 4) = w;
}

// ---------- MFMA bf16 GEMM, in-place: Z_m <- Z_m @ W_m + bias_m; grid.y = m ----------
// 16x16x32 layouts (m89/m91): A[m=lane&15][k=quad*8+j]; B[k][n=lane&15]; C col=lane&15,row=quad*4+r
__global__ __launch_bounds__(256) void mfma_gemm_kernel(unsigned short* __restrict__ zall,
                                                        const float* __restrict__ Wall,
                                                        const float* __restrict__ Ball) {
  __shared__ unsigned short Wt[128 * 136];
  int m = blockIdx.y;
  const float* Wmat = Wall + (size_t)m * DD * DD;
  const float* bias = Ball + (size_t)m * DD;
  unsigned short* Z = zall + (size_t)m * NN * DD;
  int t = threadIdx.x;
  {
    uint32_hip* Wt_u = (uint32_hip*)Wt;
#pragma unroll
    for (int i = 0; i < 32; ++i) {
      int idx = i * 256 + t;
      int k2 = idx >> 7;
      int nn = idx & 127;
      float w0 = Wmat[(2 * k2) * 128 + nn];
      float w1 = Wmat[(2 * k2 + 1) * 128 + nn];
      Wt_u[nn * 68 + k2] = packbf2(w0, w1);
    }
  }
  __syncthreads();
  int wave = t >> 6, lane = t & 63;
  int quad = lane >> 4, ln = lane & 15;
  int rowbase = blockIdx.x * 64 + wave * 16;
  int arow = rowbase + ln;
  int arowc = (arow < NN) ? arow : (NN - 1);
  const short8* zrow = (const short8*)(Z + (size_t)arowc * 128);
  floatx4 acc[8];
#pragma unroll
  for (int c = 0; c < 8; ++c) acc[c] = (floatx4){0.f, 0.f, 0.f, 0.f};
#pragma unroll
  for (int kt = 0; kt < 4; ++kt) {
    short8 a = zrow[kt * 4 + quad];
#pragma unroll
    for (int c = 0; c < 8; ++c) {
      const short8* bp = (const short8*)(Wt + (c * 16 + ln) * 136 + kt * 32 + quad * 8);
      acc[c] = __builtin_amdgcn_mfma_f32_16x16x32_bf16(a, *bp, acc[c], 0, 0, 0);
    }
  }
#pragma unroll
  for (int c = 0; c < 8; ++c) {
    int col = c * 16 + ln;
    float bs = bias[col];
#pragma unroll
    for (int r = 0; r < 4; ++r) {
      int grow = rowbase + quad * 4 + r;
      if (grow < NN) Z[(size_t)grow * 128 + col] = f2bf(acc[c][r] + bs);
    }
  }
}

// ---------- fused semantic attention + softmax-combine (+ final log_softmax) ----------
// Wave covers 16 nodes; A-frags for all 3 m retained in regs; scores via MFMA; combine from regs.
// l==0 writes fp8 h (x64); l==1 writes fp32 log_softmax.
__global__ __launch_bounds__(256) void att_combine_kernel(
    const unsigned short* __restrict__ Z, const float* __restrict__ W1,
    const float* __restrict__ b1, const float* __restrict__ w2,
    uint32_hip* __restrict__ hq, float* __restrict__ fout, int last) {
  __shared__ unsigned short Wt[128 * 136];
  __shared__ float sc[4][3][16];
  int t = threadIdx.x;
  {
    uint32_hip* Wt_u = (uint32_hip*)Wt;
#pragma unroll
    for (int i = 0; i < 32; ++i) {
      int idx = i * 256 + t;
      int k2 = idx >> 7;
      int nn = idx & 127;
      float w0 = W1[(2 * k2) * 128 + nn];
      float w1 = W1[(2 * k2 + 1) * 128 + nn];
      Wt_u[nn * 68 + k2] = packbf2(w0, w1);
    }
  }
  __syncthreads();
  int wave = t >> 6, lane = t & 63;
  int quad = lane >> 4, ln = lane & 15;
  int nodebase = blockIdx.x * 64 + wave * 16;
  int frow = nodebase + ln;
  int frowc = (frow < NN) ? frow : (NN - 1);
  short8 af[3][4];
#pragma unroll
  for (int m = 0; m < 3; ++m) {
    const short8* zr = (const short8*)(Z + ((size_t)m * NN + frowc) * 128);
#pragma unroll
    for (int kt = 0; kt < 4; ++kt) af[m][kt] = zr[kt * 4 + quad];
  }
  // attention scores per m
#pragma unroll
  for (int m = 0; m < 3; ++m) {
    floatx4 acc[8];
#pragma unroll
    for (int c = 0; c < 8; ++c) acc[c] = (floatx4){0.f, 0.f, 0.f, 0.f};
#pragma unroll
    for (int kt = 0; kt < 4; ++kt) {
#pragma unroll
      for (int c = 0; c < 8; ++c) {
        const short8* bp = (const short8*)(Wt + (c * 16 + ln) * 136 + kt * 32 + quad * 8);
        acc[c] = __builtin_amdgcn_mfma_f32_16x16x32_bf16(af[m][kt], *bp, acc[c], 0, 0, 0);
      }
    }
    float rows[4] = {0.f, 0.f, 0.f, 0.f};
#pragma unroll
    for (int c = 0; c < 8; ++c) {
      int col = c * 16 + ln;
      float bb = b1[col];
      float ww = w2[col];
#pragma unroll
      for (int r = 0; r < 4; ++r) rows[r] += tanh_apx(acc[c][r] + bb) * ww;
    }
#pragma unroll
    for (int off = 8; off > 0; off >>= 1) {
#pragma unroll
      for (int r = 0; r < 4; ++r) rows[r] += __shfl_down(rows[r], off);
    }
    if (ln == 0) {
#pragma unroll
      for (int r = 0; r < 4; ++r) sc[wave][m][quad * 4 + r] = rows[r];
    }
  }
  __syncthreads();
  // combine: lane handles node `frow` (cols kt*32 + quad*8 + j)
  float s0 = sc[wave][0][ln], s1 = sc[wave][1][ln], s2 = sc[wave][2][ln];
  float mx = fmaxf(s0, fmaxf(s1, s2));
  float e0 = __expf(s0 - mx), e1 = __expf(s1 - mx), e2 = __expf(s2 - mx);
  float inv = 1.0f / (e0 + e1 + e2);
  float bb0 = e0 * inv, bb1 = e1 * inv, bb2 = e2 * inv;
  float o[4][8];
#pragma unroll
  for (int kt = 0; kt < 4; ++kt) {
#pragma unroll
    for (int j = 0; j < 8; ++j) {
      o[kt][j] = bb0 * bf2f(af[0][kt][j]) + bb1 * bf2f(af[1][kt][j]) + bb2 * bf2f(af[2][kt][j]);
    }
  }
  if (!last) {
    if (frow < NN) {
#pragma unroll
      for (int kt = 0; kt < 4; ++kt) {
        uint2 v;
        v.x = pack_fp8x4(o[kt][0] * HSCALE, o[kt][1] * HSCALE, o[kt][2] * HSCALE,
                         o[kt][3] * HSCALE);
        v.y = pack_fp8x4(o[kt][4] * HSCALE, o[kt][5] * HSCALE, o[kt][6] * HSCALE,
                         o[kt][7] * HSCALE);
        *(uint2*)&hq[(size_t)frow * 32 + kt * 8 + quad * 2] = v;
      }
    }
  } else {
    float vmx = o[0][0];
#pragma unroll
    for (int kt = 0; kt < 4; ++kt)
#pragma unroll
      for (int j = 0; j < 8; ++j) vmx = fmaxf(vmx, o[kt][j]);
    vmx = fmaxf(vmx, __shfl_xor(vmx, 16));
    vmx = fmaxf(vmx, __shfl_xor(vmx, 32));
    float ss = 0.f;
#pragma unroll
    for (int kt = 0; kt < 4; ++kt)
#pragma unroll
      for (int j = 0; j < 8; ++j) ss += __expf(o[kt][j] - vmx);
    ss += __shfl_xor(ss, 16);
    ss += __shfl_xor(ss, 32);
    float lse = vmx + logf(ss);
    if (frow < NN) {
#pragma unroll
      for (int kt = 0; kt < 4; ++kt) {
        float4 a, b;
        a.x = o[kt][0] - lse; a.y = o[kt][1] - lse; a.z = o[kt][2] - lse; a.w = o[kt][3] - lse;
        b.x = o[kt][4] - lse; b.y = o[kt][5] - lse; b.z = o[kt][6] - lse; b.w = o[kt][7] - lse;
        float* dst = fout + (size_t)frow * 128 + kt * 32 + quad * 8;
        *(float4*)dst = a;
        *(float4*)(dst + 4) = b;
      }
    }
  }
}

extern "C" void kernel_launch(void* const* d_in, const int* in_sizes, int n_in,
                              void* d_out, int out_size, void* d_ws, size_t ws_size,
                              hipStream_t stream) {
  const int* x = (const int*)d_in[0];
  const int* e0 = (const int*)d_in[1];
  const int* e1 = (const int*)d_in[2];
  const int* e2 = (const int*)d_in[3];
  const float* embed = (const float*)d_in[4];
  const float* W = (const float*)d_in[5];    // [2][3][128][128]
  const float* B = (const float*)d_in[6];    // [2][3][128]
  const float* aw1 = (const float*)d_in[7];  // [2][128][128]
  const float* ab1 = (const float*)d_in[8];  // [2][128]
  const float* aw2 = (const float*)d_in[9];  // [2][128]
  float* out = (float*)d_out;
  uint32_hip* hq = (uint32_hip*)d_out;  // fp8 h (12.8MB) lives in d_out until final layer

  char* ws = (char*)d_ws;
  size_t off = 0;
  auto alloc = [&](size_t bytes) {
    void* p = ws + off;
    off += (bytes + 255) & ~(size_t)255;
    return p;
  };
  unsigned short* z = (unsigned short*)alloc((size_t)MM * NN * DD * 2);  // 76.8 MB
  uint32_hip* ebuf = (uint32_hip*)alloc((size_t)MM * CSRTOT * 4);        // 21.9 MB (becomes CSR)
  int* astart = (int*)alloc((size_t)MM * NN * 4);                        // 1.2 MB
  unsigned short* sdeg = (unsigned short*)alloc((size_t)MM * NN * 2);    // 0.6 MB
  int* bcur = (int*)alloc((size_t)MM * NBUK * 4);                        // ~9 KB
  int* thist = (int*)alloc((size_t)MM * NBUK * TH_PITCH * 4);            // 7.4 MB

  dim3 bs(256);
  hist_kernel<<<dim3(NTILES, 3), bs, 0, stream>>>(e0, e1, e2, thist);
  scan_kernel<<<dim3(NBUK, 3), bs, 0, stream>>>(thist, bcur);
  scatter_kernel<<<dim3(NTILES, 3), bs, 0, stream>>>(e0, e1, e2, thist, ebuf);
  bucket_sort_kernel<<<dim3(NBUK, 3), bs, 0, stream>>>(ebuf, bcur, astart, sdeg);
  norm_embed_kernel<<<dim3(NBUK, 3), bs, 0, stream>>>(ebuf, bcur, sdeg);
  embed_kernel<<<dim3((NN * 32 + 255) / 256), bs, 0, stream>>>(x, embed, hq);

  for (int l = 0; l < 2; ++l) {
    agg_kernel<<<dim3((NN + 15) / 16, 3), bs, 0, stream>>>(
        (const uint32_hip*)hq, sdeg, astart, ebuf, (uint32_hip*)z);
    mfma_gemm_kernel<<<dim3((NN + 63) / 64, 3), bs, 0, stream>>>(
        z, W + (size_t)l * 3 * DD * DD, B + (size_t)l * 3 * DD);
    att_combine_kernel<<<dim3((NN + 63) / 64), bs, 0, stream>>>(
        z, aw1 + (size_t)l * DD * DD, ab1 + (size_t)l * DD, aw2 + (size_t)l * DD, hq, out, l == 1);
  }
}

// Round 4
// 650.729 us; speedup vs baseline: 1.1265x; 1.1265x over previous
//
#include <hip/hip_runtime.h>
#include <hip/hip_bf16.h>

#define NN 100000
#define DD 128
#define MM 3
#define EE 1600000
#define CH_NODES 512                          // nodes per coarse chunk
#define NC ((NN + CH_NODES - 1) / CH_NODES)   // 196 coarse chunks
#define ECAP 8960                             // per-chunk edge capacity (mean 8192, +8.5 sigma)
#define ECHTOT ((size_t)NC * ECAP)            // per-m CSR capacity
#define TILE_E 8192
#define NTILES ((EE + TILE_E - 1) / TILE_E)   // 196
#define HSCALE 64.0f
#define HINV (1.0f / 64.0f)

typedef unsigned int uint32_hip;
typedef short short8 __attribute__((ext_vector_type(8)));
typedef float floatx4 __attribute__((ext_vector_type(4)));
typedef float floatx2 __attribute__((ext_vector_type(2)));

// ---- bf16 helpers ----
__device__ __forceinline__ float bf2f(short s) {
  return __uint_as_float(((uint32_hip)(unsigned short)s) << 16);
}
__device__ __forceinline__ unsigned short f2bf(float f) {
  union { __hip_bfloat16 b; unsigned short u; } cv;
  cv.b = __float2bfloat16(f);
  return cv.u;
}
__device__ __forceinline__ uint32_hip packbf2(float x, float y) {
  return (uint32_hip)f2bf(x) | ((uint32_hip)f2bf(y) << 16);
}
__device__ __forceinline__ float tanh_apx(float x) {
  float e = __expf(2.0f * x);
  return 1.0f - 2.0f / (e + 1.0f);
}
// pack 4 floats -> 4 fp8 e4m3 (OCP on gfx950) in one uint
__device__ __forceinline__ uint32_hip pack_fp8x4(float a, float b, float c, float d) {
  uint32_hip w = 0;
  w = __builtin_amdgcn_cvt_pk_fp8_f32(a, b, w, false);  // bytes 0,1
  w = __builtin_amdgcn_cvt_pk_fp8_f32(c, d, w, true);   // bytes 2,3
  return w;
}
// fp16 (in low 16 bits) -> f32
__device__ __forceinline__ float h2f(uint32_hip u) {
  union { unsigned short us; _Float16 h; } cv;
  cv.us = (unsigned short)u;
  return (float)cv.h;
}
__device__ __forceinline__ unsigned short f2h(float f) {
  union { unsigned short us; _Float16 h; } cv;
  cv.h = (_Float16)f;
  return cv.us;
}
// decode 8 fp8 (uint2) -> 8 floats
__device__ __forceinline__ void dec8(uint2 hv, float* f) {
  floatx2 p0 = __builtin_amdgcn_cvt_pk_f32_fp8((int)hv.x, false);
  floatx2 p1 = __builtin_amdgcn_cvt_pk_f32_fp8((int)hv.x, true);
  floatx2 p2 = __builtin_amdgcn_cvt_pk_f32_fp8((int)hv.y, false);
  floatx2 p3 = __builtin_amdgcn_cvt_pk_f32_fp8((int)hv.y, true);
  f[0] = p0.x; f[1] = p0.y; f[2] = p1.x; f[3] = p1.y;
  f[4] = p2.x; f[5] = p2.y; f[6] = p3.x; f[7] = p3.y;
}

// ---------- L1 pass A: per-tile coarse-chunk histogram -> thist[m][chunk][tile] ----------
__global__ __launch_bounds__(256) void hist1_kernel(const int* __restrict__ e0,
                                                    const int* __restrict__ e1,
                                                    const int* __restrict__ e2,
                                                    int* __restrict__ thist) {
  __shared__ int hist[NC];
  int m = blockIdx.y, tile = blockIdx.x, t = threadIdx.x;
  const int* ei = (m == 0) ? e0 : (m == 1) ? e1 : e2;
  const int* dst = ei + EE;
  int beg = tile * TILE_E, end = min(beg + TILE_E, EE);
  if (t < NC) hist[t] = 0;
  __syncthreads();
  for (int e = beg + t; e < end; e += 256) atomicAdd(&hist[dst[e] >> 9], 1);
  __syncthreads();
  int* th = thist + (size_t)m * NC * NTILES + tile;
  if (t < NC) th[(size_t)t * NTILES] = hist[t];
}

// ---------- L1 pass B: exclusive scan across tiles per (chunk,m) -> deterministic bases ----
// thist[m][c][t] <- c*ECAP + prefix; ccount[m][c] = chunk total
__global__ __launch_bounds__(256) void scan1_kernel(int* __restrict__ thist,
                                                    int* __restrict__ ccount) {
  __shared__ int sw[256];
  int c = blockIdx.x, m = blockIdx.y, t = threadIdx.x;
  int* th = thist + ((size_t)m * NC + c) * NTILES;
  int v = (t < NTILES) ? th[t] : 0;
  sw[t] = v;
  __syncthreads();
  for (int off = 1; off < 256; off <<= 1) {
    int u = (t >= off) ? sw[t - off] : 0;
    __syncthreads();
    sw[t] += u;
    __syncthreads();
  }
  if (t < NTILES) th[t] = c * ECAP + sw[t] - v;  // exclusive base
  if (t == NTILES - 1) ccount[m * NC + c] = sw[t];
}

// ---------- L1 pass C: coarse scatter, LDS-sorted emit (runs of ~42 edges) ----------
// entry = src | (dst&511)<<17  (26 bits)
__global__ __launch_bounds__(256) void scatter1_kernel(const int* __restrict__ e0,
                                                       const int* __restrict__ e1,
                                                       const int* __restrict__ e2,
                                                       const int* __restrict__ thist,
                                                       const int* __restrict__ ccount,
                                                       uint32_hip* __restrict__ lvl1) {
  __shared__ int gbase[NC];
  __shared__ int spos[NC];
  __shared__ int cur[NC];
  __shared__ int sw[256];
  __shared__ uint32_hip sval[TILE_E];
  __shared__ unsigned char sbuk[TILE_E];
  int m = blockIdx.y, tile = blockIdx.x, t = threadIdx.x;
  const int* ei = (m == 0) ? e0 : (m == 1) ? e1 : e2;
  const int* dst = ei + EE;
  const int* th = thist + (size_t)m * NC * NTILES + tile;
  int cnt = 0;
  if (t < NC) {
    int gb = th[(size_t)t * NTILES];
    int gn = (tile + 1 < NTILES) ? th[(size_t)t * NTILES + 1] : t * ECAP + ccount[m * NC + t];
    gbase[t] = gb;
    cnt = gn - gb;  // this tile's count for chunk t (derived, no re-histogram)
  }
  sw[t] = cnt;
  __syncthreads();
  for (int off = 1; off < 256; off <<= 1) {
    int u = (t >= off) ? sw[t - off] : 0;
    __syncthreads();
    sw[t] += u;
    __syncthreads();
  }
  if (t < NC) {
    spos[t] = sw[t] - cnt;
    cur[t] = sw[t] - cnt;
  }
  __syncthreads();
  int beg = tile * TILE_E, end = min(beg + TILE_E, EE);
  int ct = end - beg;
  for (int e = beg + t; e < end; e += 256) {
    int s = ei[e], d = dst[e];
    int b = d >> 9;
    int r = atomicAdd(&cur[b], 1);
    sval[r] = (uint32_hip)s | ((uint32_hip)(d & 511) << 17);
    sbuk[r] = (unsigned char)b;
  }
  __syncthreads();
  uint32_hip* eb = lvl1 + (size_t)m * ECHTOT;
  for (int i = t; i < ct; i += 256) {
    int b = sbuk[i];
    eb[gbase[b] + (i - spos[b])] = sval[i];
  }
}

// ---------- L2: per-chunk 512-way counting sort in LDS; emits astart + sdeg ----------
// Replaces fine scatter + bucket_sort. In-place on lvl1 (becomes final CSR, src-only).
__global__ __launch_bounds__(256) void sort2_kernel(uint32_hip* __restrict__ lvl1,
                                                    const int* __restrict__ ccount,
                                                    int* __restrict__ astart,
                                                    unsigned short* __restrict__ sdeg) {
  __shared__ uint32_hip ebl[ECAP];
  __shared__ int cnt[CH_NODES];
  __shared__ int pos[CH_NODES];
  __shared__ int sw[256];
  int m = blockIdx.y, c = blockIdx.x, t = threadIdx.x;
  int base = c * ECAP;
  int ct = ccount[m * NC + c];
  uint32_hip* eb = lvl1 + (size_t)m * ECHTOT + base;
  for (int e = t; e < ct; e += 256) ebl[e] = eb[e];
  cnt[t] = 0;
  cnt[t + 256] = 0;
  __syncthreads();
  for (int e = t; e < ct; e += 256) atomicAdd(&cnt[ebl[e] >> 17], 1);
  __syncthreads();
  int c0 = cnt[2 * t], c1 = cnt[2 * t + 1];
  int s = c0 + c1;
  sw[t] = s;
  __syncthreads();
  for (int off = 1; off < 256; off <<= 1) {
    int u = (t >= off) ? sw[t - off] : 0;
    __syncthreads();
    sw[t] += u;
    __syncthreads();
  }
  int excl = sw[t] - s;
  pos[2 * t] = excl;
  pos[2 * t + 1] = excl + c0;
  int node0 = c * CH_NODES;
  {
    int n0 = node0 + 2 * t;
    if (n0 < NN) {
      astart[(size_t)m * NN + n0] = base + excl;
      sdeg[(size_t)m * NN + n0] = (unsigned short)c0;
    }
    int n1 = node0 + 2 * t + 1;
    if (n1 < NN) {
      astart[(size_t)m * NN + n1] = base + excl + c0;
      sdeg[(size_t)m * NN + n1] = (unsigned short)c1;
    }
  }
  __syncthreads();
  for (int e = t; e < ct; e += 256) {
    uint32_hip p = ebl[e];
    int q = atomicAdd(&pos[p >> 17], 1);
    eb[q] = p & 0x1FFFFu;  // src only, node-sorted, in place
  }
}

// ---------- embed fp16 source-norm into upper 15 bits of each CSR entry ----------
// entry = src | (fp16(rsqrt(deg[src]+1)) << 17). sdeg (200KB/m) is L2-resident.
__global__ void norm_embed_kernel(uint32_hip* __restrict__ lvl1, const int* __restrict__ ccount,
                                  const unsigned short* __restrict__ sdeg) {
  int m = blockIdx.y, c = blockIdx.x, t = threadIdx.x;
  int base = c * ECAP;
  int ct = ccount[m * NC + c];
  uint32_hip* eb = lvl1 + (size_t)m * ECHTOT + base;
  const unsigned short* sd = sdeg + (size_t)m * NN;
  for (int e = t; e < ct; e += 256) {
    uint32_hip s = eb[e] & 0x1FFFFu;
    float dv = rsqrtf((float)(sd[s] + 1));
    eb[e] = s | ((uint32_hip)f2h(dv) << 17);
  }
}

// ---------- embedding gather -> fp8 h (x64 scale), lives in d_out ----------
__global__ void embed_kernel(const int* __restrict__ x, const float* __restrict__ tbl,
                             uint32_hip* __restrict__ hq) {
  int i = blockIdx.x * 256 + threadIdx.x;
  if (i < NN * 32) {
    int n = i >> 5;
    int c = i & 31;
    float4 v = ((const float4*)tbl)[(size_t)x[n] * 32 + c];
    hq[(size_t)n * 32 + c] =
        pack_fp8x4(v.x * HSCALE, v.y * HSCALE, v.z * HSCALE, v.w * HSCALE);
  }
}

// ---------- normalized aggregation (fp8 h -> bf16 z) ----------
// 4 nodes per wave, 16 lanes per node, dwordx2 (8 fp8) per lane per edge.
__global__ __launch_bounds__(256) void agg_kernel(const uint32_hip* __restrict__ hq,
                                                  const unsigned short* __restrict__ sdeg,
                                                  const int* __restrict__ astart,
                                                  const uint32_hip* __restrict__ csr,
                                                  uint32_hip* __restrict__ zall) {
  int m = blockIdx.y;
  const unsigned short* sd = sdeg + (size_t)m * NN;
  const int* as_ = astart + (size_t)m * NN;
  const uint32_hip* cs = csr + (size_t)m * ECHTOT;
  uint32_hip* zo = zall + (size_t)m * NN * 64;
  int t = threadIdx.x;
  int wave = t >> 6, lane = t & 63;
  int g = lane >> 4, l = lane & 15;  // group (node) within wave, lane within group
  int n = blockIdx.x * 16 + wave * 4 + g;  // NN = 100000 = 16 * 6250 -> exact grid
  int deg = sd[n];
  float di = rsqrtf((float)(deg + 1));

  float ac[8];
  {
    uint2 hv = *(const uint2*)(hq + (size_t)n * 32 + l * 2);
    float f[8];
    dec8(hv, f);
#pragma unroll
    for (int j = 0; j < 8; ++j) ac[j] = di * f[j];
  }

  int e = as_[n];
  int end = e + deg;
  bool v0 = e < end, v1 = (e + 1) < end;
  uint32_hip c0 = cs[v0 ? e : 0];
  uint32_hip c1 = cs[v1 ? e + 1 : 0];
  while (__any(v0)) {
    int en = e + 2;
    bool u0 = en < end, u1 = (en + 1) < end;
    uint32_hip d0 = cs[u0 ? en : 0];
    uint32_hip d1 = cs[u1 ? en + 1 : 0];
    float n0 = v0 ? h2f(c0 >> 17) : 0.f;
    float n1 = v1 ? h2f(c1 >> 17) : 0.f;
    int s0 = c0 & 0x1FFFF, s1 = c1 & 0x1FFFF;
    uint2 h0 = *(const uint2*)(hq + (size_t)s0 * 32 + l * 2);
    uint2 h1 = *(const uint2*)(hq + (size_t)s1 * 32 + l * 2);
    float f0[8], f1[8];
    dec8(h0, f0);
    dec8(h1, f1);
#pragma unroll
    for (int j = 0; j < 8; ++j) ac[j] = fmaf(n0, f0[j], ac[j]);
#pragma unroll
    for (int j = 0; j < 8; ++j) ac[j] = fmaf(n1, f1[j], ac[j]);
    e = en;
    v0 = u0;
    v1 = u1;
    c0 = d0;
    c1 = d1;
  }

  float sc = di * HINV;
  uint4 w;
  w.x = packbf2(ac[0] * sc, ac[1] * sc);
  w.y = packbf2(ac[2] * sc, ac[3] * sc);
  w.z = packbf2(ac[4] * sc, ac[5] * sc);
  w.w = packbf2(ac[6] * sc, ac[7] * sc);
  *(uint4*)(zo + (size_t)n * 64 + l * 4) = w;
}

// ---------- MFMA bf16 GEMM, in-place: Z_m <- Z_m @ W_m + bias_m; grid.y = m ----------
__global__ __launch_bounds__(256) void mfma_gemm_kernel(unsigned short* __restrict__ zall,
                                                        const float* __restrict__ Wall,
                                                        const float* __restrict__ Ball) {
  __shared__ unsigned short Wt[128 * 136];
  int m = blockIdx.y;
  const float* Wmat = Wall + (size_t)m * DD * DD;
  const float* bias = Ball + (size_t)m * DD;
  unsigned short* Z = zall + (size_t)m * NN * DD;
  int t = threadIdx.x;
  {
    uint32_hip* Wt_u = (uint32_hip*)Wt;
#pragma unroll
    for (int i = 0; i < 32; ++i) {
      int idx = i * 256 + t;
      int k2 = idx >> 7;
      int nn = idx & 127;
      float w0 = Wmat[(2 * k2) * 128 + nn];
      float w1 = Wmat[(2 * k2 + 1) * 128 + nn];
      Wt_u[nn * 68 + k2] = packbf2(w0, w1);
    }
  }
  __syncthreads();
  int wave = t >> 6, lane = t & 63;
  int quad = lane >> 4, ln = lane & 15;
  int rowbase = blockIdx.x * 64 + wave * 16;
  int arow = rowbase + ln;
  int arowc = (arow < NN) ? arow : (NN - 1);
  const short8* zrow = (const short8*)(Z + (size_t)arowc * 128);
  floatx4 acc[8];
#pragma unroll
  for (int c = 0; c < 8; ++c) acc[c] = (floatx4){0.f, 0.f, 0.f, 0.f};
#pragma unroll
  for (int kt = 0; kt < 4; ++kt) {
    short8 a = zrow[kt * 4 + quad];
#pragma unroll
    for (int c = 0; c < 8; ++c) {
      const short8* bp = (const short8*)(Wt + (c * 16 + ln) * 136 + kt * 32 + quad * 8);
      acc[c] = __builtin_amdgcn_mfma_f32_16x16x32_bf16(a, *bp, acc[c], 0, 0, 0);
    }
  }
#pragma unroll
  for (int c = 0; c < 8; ++c) {
    int col = c * 16 + ln;
    float bs = bias[col];
#pragma unroll
    for (int r = 0; r < 4; ++r) {
      int grow = rowbase + quad * 4 + r;
      if (grow < NN) Z[(size_t)grow * 128 + col] = f2bf(acc[c][r] + bs);
    }
  }
}

// ---------- fused semantic attention + softmax-combine (+ final log_softmax) ----------
__global__ __launch_bounds__(256) void att_combine_kernel(
    const unsigned short* __restrict__ Z, const float* __restrict__ W1,
    const float* __restrict__ b1, const float* __restrict__ w2,
    uint32_hip* __restrict__ hq, float* __restrict__ fout, int last) {
  __shared__ unsigned short Wt[128 * 136];
  __shared__ float sc[4][3][16];
  int t = threadIdx.x;
  {
    uint32_hip* Wt_u = (uint32_hip*)Wt;
#pragma unroll
    for (int i = 0; i < 32; ++i) {
      int idx = i * 256 + t;
      int k2 = idx >> 7;
      int nn = idx & 127;
      float w0 = W1[(2 * k2) * 128 + nn];
      float w1 = W1[(2 * k2 + 1) * 128 + nn];
      Wt_u[nn * 68 + k2] = packbf2(w0, w1);
    }
  }
  __syncthreads();
  int wave = t >> 6, lane = t & 63;
  int quad = lane >> 4, ln = lane & 15;
  int nodebase = blockIdx.x * 64 + wave * 16;
  int frow = nodebase + ln;
  int frowc = (frow < NN) ? frow : (NN - 1);
  short8 af[3][4];
#pragma unroll
  for (int m = 0; m < 3; ++m) {
    const short8* zr = (const short8*)(Z + ((size_t)m * NN + frowc) * 128);
#pragma unroll
    for (int kt = 0; kt < 4; ++kt) af[m][kt] = zr[kt * 4 + quad];
  }
#pragma unroll
  for (int m = 0; m < 3; ++m) {
    floatx4 acc[8];
#pragma unroll
    for (int c = 0; c < 8; ++c) acc[c] = (floatx4){0.f, 0.f, 0.f, 0.f};
#pragma unroll
    for (int kt = 0; kt < 4; ++kt) {
#pragma unroll
      for (int c = 0; c < 8; ++c) {
        const short8* bp = (const short8*)(Wt + (c * 16 + ln) * 136 + kt * 32 + quad * 8);
        acc[c] = __builtin_amdgcn_mfma_f32_16x16x32_bf16(af[m][kt], *bp, acc[c], 0, 0, 0);
      }
    }
    float rows[4] = {0.f, 0.f, 0.f, 0.f};
#pragma unroll
    for (int c = 0; c < 8; ++c) {
      int col = c * 16 + ln;
      float bb = b1[col];
      float ww = w2[col];
#pragma unroll
      for (int r = 0; r < 4; ++r) rows[r] += tanh_apx(acc[c][r] + bb) * ww;
    }
#pragma unroll
    for (int off = 8; off > 0; off >>= 1) {
#pragma unroll
      for (int r = 0; r < 4; ++r) rows[r] += __shfl_down(rows[r], off);
    }
    if (ln == 0) {
#pragma unroll
      for (int r = 0; r < 4; ++r) sc[wave][m][quad * 4 + r] = rows[r];
    }
  }
  __syncthreads();
  float s0 = sc[wave][0][ln], s1 = sc[wave][1][ln], s2 = sc[wave][2][ln];
  float mx = fmaxf(s0, fmaxf(s1, s2));
  float e0 = __expf(s0 - mx), e1 = __expf(s1 - mx), e2 = __expf(s2 - mx);
  float inv = 1.0f / (e0 + e1 + e2);
  float bb0 = e0 * inv, bb1 = e1 * inv, bb2 = e2 * inv;
  float o[4][8];
#pragma unroll
  for (int kt = 0; kt < 4; ++kt) {
#pragma unroll
    for (int j = 0; j < 8; ++j) {
      o[kt][j] = bb0 * bf2f(af[0][kt][j]) + bb1 * bf2f(af[1][kt][j]) + bb2 * bf2f(af[2][kt][j]);
    }
  }
  if (!last) {
    if (frow < NN) {
#pragma unroll
      for (int kt = 0; kt < 4; ++kt) {
        uint2 v;
        v.x = pack_fp8x4(o[kt][0] * HSCALE, o[kt][1] * HSCALE, o[kt][2] * HSCALE,
                         o[kt][3] * HSCALE);
        v.y = pack_fp8x4(o[kt][4] * HSCALE, o[kt][5] * HSCALE, o[kt][6] * HSCALE,
                         o[kt][7] * HSCALE);
        *(uint2*)&hq[(size_t)frow * 32 + kt * 8 + quad * 2] = v;
      }
    }
  } else {
    float vmx = o[0][0];
#pragma unroll
    for (int kt = 0; kt < 4; ++kt)
#pragma unroll
      for (int j = 0; j < 8; ++j) vmx = fmaxf(vmx, o[kt][j]);
    vmx = fmaxf(vmx, __shfl_xor(vmx, 16));
    vmx = fmaxf(vmx, __shfl_xor(vmx, 32));
    float ss = 0.f;
#pragma unroll
    for (int kt = 0; kt < 4; ++kt)
#pragma unroll
      for (int j = 0; j < 8; ++j) ss += __expf(o[kt][j] - vmx);
    ss += __shfl_xor(ss, 16);
    ss += __shfl_xor(ss, 32);
    float lse = vmx + logf(ss);
    if (frow < NN) {
#pragma unroll
      for (int kt = 0; kt < 4; ++kt) {
        float4 a, b;
        a.x = o[kt][0] - lse; a.y = o[kt][1] - lse; a.z = o[kt][2] - lse; a.w = o[kt][3] - lse;
        b.x = o[kt][4] - lse; b.y = o[kt][5] - lse; b.z = o[kt][6] - lse; b.w = o[kt][7] - lse;
        float* dst = fout + (size_t)frow * 128 + kt * 32 + quad * 8;
        *(float4*)dst = a;
        *(float4*)(dst + 4) = b;
      }
    }
  }
}

extern "C" void kernel_launch(void* const* d_in, const int* in_sizes, int n_in,
                              void* d_out, int out_size, void* d_ws, size_t ws_size,
                              hipStream_t stream) {
  const int* x = (const int*)d_in[0];
  const int* e0 = (const int*)d_in[1];
  const int* e1 = (const int*)d_in[2];
  const int* e2 = (const int*)d_in[3];
  const float* embed = (const float*)d_in[4];
  const float* W = (const float*)d_in[5];    // [2][3][128][128]
  const float* B = (const float*)d_in[6];    // [2][3][128]
  const float* aw1 = (const float*)d_in[7];  // [2][128][128]
  const float* ab1 = (const float*)d_in[8];  // [2][128]
  const float* aw2 = (const float*)d_in[9];  // [2][128]
  float* out = (float*)d_out;
  uint32_hip* hq = (uint32_hip*)d_out;  // fp8 h (12.8MB) lives in d_out until final layer

  char* ws = (char*)d_ws;
  size_t off = 0;
  auto alloc = [&](size_t bytes) {
    void* p = ws + off;
    off += (bytes + 255) & ~(size_t)255;
    return p;
  };
  unsigned short* z = (unsigned short*)alloc((size_t)MM * NN * DD * 2);  // 76.8 MB
  uint32_hip* lvl1 = (uint32_hip*)alloc((size_t)MM * ECHTOT * 4);        // 21.1 MB (becomes CSR)
  int* astart = (int*)alloc((size_t)MM * NN * 4);                        // 1.2 MB
  unsigned short* sdeg = (unsigned short*)alloc((size_t)MM * NN * 2);    // 0.6 MB
  int* ccount = (int*)alloc((size_t)MM * NC * 4);                        // ~2.4 KB
  int* thist = (int*)alloc((size_t)MM * NC * NTILES * 4);                // ~0.5 MB

  dim3 bs(256);
  hist1_kernel<<<dim3(NTILES, 3), bs, 0, stream>>>(e0, e1, e2, thist);
  scan1_kernel<<<dim3(NC, 3), bs, 0, stream>>>(thist, ccount);
  scatter1_kernel<<<dim3(NTILES, 3), bs, 0, stream>>>(e0, e1, e2, thist, ccount, lvl1);
  sort2_kernel<<<dim3(NC, 3), bs, 0, stream>>>(lvl1, ccount, astart, sdeg);
  norm_embed_kernel<<<dim3(NC, 3), bs, 0, stream>>>(lvl1, ccount, sdeg);
  embed_kernel<<<dim3((NN * 32 + 255) / 256), bs, 0, stream>>>(x, embed, hq);

  for (int l = 0; l < 2; ++l) {
    agg_kernel<<<dim3((NN + 15) / 16, 3), bs, 0, stream>>>(
        (const uint32_hip*)hq, sdeg, astart, lvl1, (uint32_hip*)z);
    mfma_gemm_kernel<<<dim3((NN + 63) / 64, 3), bs, 0, stream>>>(
        z, W + (size_t)l * 3 * DD * DD, B + (size_t)l * 3 * DD);
    att_combine_kernel<<<dim3((NN + 63) / 64), bs, 0, stream>>>(
        z, aw1 + (size_t)l * DD * DD, ab1 + (size_t)l * DD, aw2 + (size_t)l * DD, hq, out, l == 1);
  }
}